// Round 3
// baseline (314.433 us; speedup 1.0000x reference)
//
#include <hip/hip_runtime.h>
#include <hip/hip_bf16.h>

#define NIN 1024
#define NOUT 4096
#define NTOK 4096
#define NSTACK 4
#define RANK 4

typedef __bf16 bf16x8 __attribute__((ext_vector_type(8)));
typedef float f32x4 __attribute__((ext_vector_type(4)));

// ============ fused prep ============
// blocks 0..31: build M (coalesced diagonal-band walk)
// blocks 32..2079: cast x fp32->bf16
//
// M[s,t,c] = sum_r sum_{i=0}^{min(t,c)} G[s,r,t-i]*H[s,r,c-i]
// Recurrence along diagonal: M[t][c] = M[t-1][c-1] + sum_r G_r[t]*H_r[c].
__global__ __launch_bounds__(256) void prep_kernel(const float* __restrict__ x,
                                                   const float* __restrict__ G,
                                                   const float* __restrict__ H,
                                                   __bf16* __restrict__ xb,
                                                   __bf16* __restrict__ M) {
  int bid = blockIdx.x;
  if (bid >= 32) {  // -------- cast: 2048 blocks * 2048 elems --------
    int i = ((bid - 32) * 256 + threadIdx.x) * 8;
    float4 a = *reinterpret_cast<const float4*>(x + i);
    float4 b = *reinterpret_cast<const float4*>(x + i + 4);
    bf16x8 o;
    o[0] = (__bf16)a.x; o[1] = (__bf16)a.y; o[2] = (__bf16)a.z; o[3] = (__bf16)a.w;
    o[4] = (__bf16)b.x; o[5] = (__bf16)b.y; o[6] = (__bf16)b.z; o[7] = (__bf16)b.w;
    *reinterpret_cast<bf16x8*>(xb + i) = o;
    return;
  }
  // -------- build M: 32 blocks x 4 waves = 128 bands --------
  const int s = bid >> 3;                       // stack (same for whole block)
  const int band = (bid & 7) * 4 + (threadIdx.x >> 6);  // 0..31 within stack
  const int lane = threadIdx.x & 63;
  const float* Gs = G + s * (RANK * NIN);
  const float* Hs = H + s * (RANK * NIN);
  __bf16* Ms = M + (size_t)s * NIN * NIN;

  if (band < 16) {
    // ---- upper triangle (d = c-t in [64w, 64w+63]): t=k uniform, c=k+d0+lane ----
    const int d0 = band * 64;
    const int myd = d0 + lane;
    float acc = 0.f;
    const int kmax = NIN - 1 - d0;
    #pragma unroll 4
    for (int k = 0; k <= kmax; ++k) {
      const int c = k + myd;
      const float g0 = Gs[k],           g1 = Gs[NIN + k];
      const float g2 = Gs[2 * NIN + k], g3 = Gs[3 * NIN + k];
      if (c <= NIN - 1) {
        acc += g0 * Hs[c] + g1 * Hs[NIN + c] + g2 * Hs[2 * NIN + c] + g3 * Hs[3 * NIN + c];
        Ms[(size_t)k * NIN + c] = (__bf16)acc;   // row k, contiguous cols across lanes
      }
    }
  } else {
    // ---- lower triangle (t-c = a0+lane), lane-skewed: t=a0+tau uniform, c=tau-lane ----
    const int w = band - 16;
    const int a0 = 1 + w * 64;
    const bool lactive = (a0 + lane) <= NIN - 1;
    float acc = 0.f;
    const int tmax = NIN - 1 - a0;
    #pragma unroll 4
    for (int tau = 0; tau <= tmax; ++tau) {
      const int t = a0 + tau;
      const int c = tau - lane;
      const float g0 = Gs[t],           g1 = Gs[NIN + t];
      const float g2 = Gs[2 * NIN + t], g3 = Gs[3 * NIN + t];
      if (lactive && c >= 0) {
        acc += g0 * Hs[c] + g1 * Hs[NIN + c] + g2 * Hs[2 * NIN + c] + g3 * Hs[3 * NIN + c];
        Ms[(size_t)t * NIN + c] = (__bf16)acc;   // row t, contiguous cols across lanes
      }
    }
  }
}

// ============ GEMM: C[m][n] = sum_k A[m][k]*B[n][k] + bias[n] ============
// BM=BN=256, BK=32, 512 thr / 8 waves (2Mx4N, wave tile 128x64).
// 4 LDS tile-buffers (128KB), stage tile kt+2 during kt -> consume distance
// ~2 K-tiles (covers HBM latency). ONE vmcnt(4) + ONE barrier per K-tile.
// T2 swizzle (0-conflict, verified R2), T1 XCD swizzle, T5 setprio.
#define BK 32
#define KT (NIN / BK)        // 32
#define TILEBY 32768         // A 16K + B 16K per K-tile

__device__ __forceinline__ void gload16(const char* gsrc, char* lds) {
  __builtin_amdgcn_global_load_lds(
      (const __attribute__((address_space(1))) unsigned int*)gsrc,
      (__attribute__((address_space(3))) unsigned int*)lds, 16, 0, 0);
}

__global__ __launch_bounds__(512, 2) void gemm_kernel(
    const __bf16* __restrict__ A,   // [NTOK][NIN]
    const __bf16* __restrict__ B,   // [NOUT][NIN]
    const float* __restrict__ bias, // [NOUT]
    float* __restrict__ C) {        // [NTOK][NOUT]
  __shared__ __align__(16) char smem[4 * TILEBY];  // 128 KB

  const int tid = threadIdx.x;
  const int lane = tid & 63;
  const int lo = lane & 15;
  const int hi = lane >> 4;
  const int wid = tid >> 6;
  const int wr = wid >> 2;   // 0..1
  const int wc = wid & 3;    // 0..3

  // XCD-aware block swizzle (grid 256, 256%8==0)
  const int orig = blockIdx.x;
  const int wg = (orig & 7) * 32 + (orig >> 3);
  const int bx = wg & 15;
  const int by = wg >> 4;
  const int brow = by * 256;
  const int bcol = bx * 256;

  // staging: per K-tile per thread 2 A-loads + 2 B-loads.
  // LDS dest linear; global src col = (P&63) ^ ((row>>1 &3)<<4)  [T2, rule 21]
  const char* Ab = (const char*)(A + (size_t)brow * NIN);
  const char* Bb = (const char*)(B + (size_t)bcol * NIN);
  size_t gofs[2];
  int lofs[2];
  #pragma unroll
  for (int l = 0; l < 2; ++l) {
    int P = (l * 512 + tid) * 16;          // 0..16K
    int row = P >> 6;
    int inner = (P & 63) ^ (((row >> 1) & 3) << 4);
    lofs[l] = P;
    gofs[l] = (size_t)row * (NIN * 2) + inner;
  }

  // fragment ds_read offsets (swizzled read side)
  const int kso = ((hi ^ ((lo >> 1) & 3)) << 4);
  const int abase = (wr * 128 + lo) * 64 + kso;            // + mi*1024
  const int bbase = 16384 + (wc * 64 + lo) * 64 + kso;     // + ni*1024

  f32x4 acc[8][4];
  #pragma unroll
  for (int i = 0; i < 8; ++i)
    #pragma unroll
    for (int j = 0; j < 4; ++j)
      acc[i][j] = (f32x4){0.f, 0.f, 0.f, 0.f};

  // ---- prologue: stage tiles 0 and 1 ----
  #pragma unroll
  for (int l = 0; l < 2; ++l) gload16(Ab + gofs[l], smem + lofs[l]);
  #pragma unroll
  for (int l = 0; l < 2; ++l) gload16(Bb + gofs[l], smem + 16384 + lofs[l]);
  #pragma unroll
  for (int l = 0; l < 2; ++l) gload16(Ab + 64 + gofs[l], smem + TILEBY + lofs[l]);
  #pragma unroll
  for (int l = 0; l < 2; ++l) gload16(Bb + 64 + gofs[l], smem + TILEBY + 16384 + lofs[l]);

  #pragma unroll 1
  for (int kt = 0; kt < KT; ++kt) {
    const char* buf = smem + (kt & 3) * TILEBY;
    char* sbuf = smem + ((kt + 2) & 3) * TILEBY;
    const int kg = (kt + 2) * 64;
    const bool dost = (kt + 2) < KT;

    // tile kt resident after own-loads wait + barrier (allow kt+1's 4 in flight)
    asm volatile("s_waitcnt vmcnt(4)" ::: "memory");
    __builtin_amdgcn_s_barrier();

    // ---- phase A: stage A(kt+2); read A mi0-3 + all B; MFMA mi0-3 ----
    if (dost) {
      gload16(Ab + kg + gofs[0], sbuf + lofs[0]);
      gload16(Ab + kg + gofs[1], sbuf + lofs[1]);
    }
    bf16x8 af[4], bfr[4];
    #pragma unroll
    for (int mi = 0; mi < 4; ++mi)
      af[mi] = *(const bf16x8*)(buf + abase + mi * 1024);
    #pragma unroll
    for (int ni = 0; ni < 4; ++ni)
      bfr[ni] = *(const bf16x8*)(buf + bbase + ni * 1024);
    __builtin_amdgcn_s_setprio(1);
    #pragma unroll
    for (int mi = 0; mi < 4; ++mi)
      #pragma unroll
      for (int ni = 0; ni < 4; ++ni)
        acc[mi][ni] = __builtin_amdgcn_mfma_f32_16x16x32_bf16(af[mi], bfr[ni], acc[mi][ni], 0, 0, 0);
    __builtin_amdgcn_s_setprio(0);

    // ---- phase B: stage B(kt+2); read A mi4-7; MFMA mi4-7 ----
    if (dost) {
      gload16(Bb + kg + gofs[0], sbuf + 16384 + lofs[0]);
      gload16(Bb + kg + gofs[1], sbuf + 16384 + lofs[1]);
    }
    bf16x8 af2[4];
    #pragma unroll
    for (int mi = 0; mi < 4; ++mi)
      af2[mi] = *(const bf16x8*)(buf + abase + (mi + 4) * 1024);
    __builtin_amdgcn_s_setprio(1);
    #pragma unroll
    for (int mi = 0; mi < 4; ++mi)
      #pragma unroll
      for (int ni = 0; ni < 4; ++ni)
        acc[mi + 4][ni] = __builtin_amdgcn_mfma_f32_16x16x32_bf16(af2[mi], bfr[ni], acc[mi + 4][ni], 0, 0, 0);
    __builtin_amdgcn_s_setprio(0);
  }

  // ---- epilogue: D layout col=lane&15, row=(lane>>4)*4+reg ----
  #pragma unroll
  for (int ni = 0; ni < 4; ++ni) {
    const int col = bcol + wc * 64 + ni * 16 + lo;
    const float bv = bias[col];
    #pragma unroll
    for (int mi = 0; mi < 8; ++mi) {
      const int row0 = brow + wr * 128 + mi * 16 + hi * 4;
      float* Cp = C + (size_t)row0 * NOUT + col;
      Cp[0]                = acc[mi][ni][0] + bv;
      Cp[(size_t)NOUT]     = acc[mi][ni][1] + bv;
      Cp[2 * (size_t)NOUT] = acc[mi][ni][2] + bv;
      Cp[3 * (size_t)NOUT] = acc[mi][ni][3] + bv;
    }
  }
}

extern "C" void kernel_launch(void* const* d_in, const int* in_sizes, int n_in,
                              void* d_out, int out_size, void* d_ws, size_t ws_size,
                              hipStream_t stream) {
  const float* x = (const float*)d_in[0];
  const float* G = (const float*)d_in[1];
  const float* H = (const float*)d_in[2];
  const float* bias = (const float*)d_in[3];
  float* out = (float*)d_out;

  __bf16* xb = (__bf16*)d_ws;                                    // 8 MB
  __bf16* Mb = (__bf16*)((char*)d_ws + (size_t)NTOK * NIN * 2);  // 8 MB

  prep_kernel<<<32 + 2048, 256, 0, stream>>>(x, G, H, xb, Mb);
  gemm_kernel<<<256, 512, 0, stream>>>(xb, Mb, bias, out);
}

// Round 4
// 174.941 us; speedup vs baseline: 1.7974x; 1.7974x over previous
//
#include <hip/hip_runtime.h>
#include <hip/hip_bf16.h>

#define NIN 1024
#define NOUT 4096
#define NTOK 4096
#define NSTACK 4
#define RANK 4

typedef __bf16 bf16x8 __attribute__((ext_vector_type(8)));
typedef float f32x4 __attribute__((ext_vector_type(4)));

// ============ fused prep ============
// blocks 0..255: build M (diagonal shfl-scan, LDS-staged coalesced stores)
//   block = (stack s, band of 32 diagonals d0 = band*32-1024)
// blocks 256..2303: cast x fp32->bf16
//
// M[s,t,c] = prefix along diagonal of E[t][c] = sum_r G_r[t]*H_r[c].
__global__ __launch_bounds__(256) void prep_kernel(const float* __restrict__ x,
                                                   const float* __restrict__ G,
                                                   const float* __restrict__ H,
                                                   __bf16* __restrict__ xb,
                                                   __bf16* __restrict__ M) {
  __shared__ unsigned short tile[64][34];  // [row-in-chunk][diag-in-band], 2-way max banks
  int bid = blockIdx.x;
  if (bid >= 256) {  // -------- cast: 2048 blocks * 2048 elems --------
    int i = ((bid - 256) * 256 + threadIdx.x) * 8;
    float4 a = *reinterpret_cast<const float4*>(x + i);
    float4 b = *reinterpret_cast<const float4*>(x + i + 4);
    bf16x8 o;
    o[0] = (__bf16)a.x; o[1] = (__bf16)a.y; o[2] = (__bf16)a.z; o[3] = (__bf16)a.w;
    o[4] = (__bf16)b.x; o[5] = (__bf16)b.y; o[6] = (__bf16)b.z; o[7] = (__bf16)b.w;
    *reinterpret_cast<bf16x8*>(xb + i) = o;
    return;
  }
  // -------- build M --------
  const int s = bid >> 6;           // stack
  const int band = bid & 63;        // 64 bands of 32 diagonals
  const int d0 = band * 32 - 1024;  // diagonals d0 .. d0+31 (d = c - t)
  const int w = threadIdx.x >> 6;
  const int lane = threadIdx.x & 63;
  const float* Gs = G + s * (RANK * NIN);
  const float* Hs = H + s * (RANK * NIN);
  unsigned short* Ms = (unsigned short*)(M + (size_t)s * NIN * NIN);

  // valid rows t: exists d in band with 0 <= t+d < NIN
  int kstart = -(d0 + 31); if (kstart < 0) kstart = 0;
  kstart &= ~63;
  int kend = NIN - d0; if (kend > NIN) kend = NIN;

  float carry[8];
  #pragma unroll
  for (int j = 0; j < 8; ++j) carry[j] = 0.f;

  for (int k0 = kstart; k0 < kend; k0 += 64) {
    const int t = k0 + lane;
    const float g0 = Gs[t], g1 = Gs[NIN + t], g2 = Gs[2 * NIN + t], g3 = Gs[3 * NIN + t];
    #pragma unroll
    for (int j = 0; j < 8; ++j) {
      const int dj = w * 8 + j;            // diag index within band
      const int c = t + d0 + dj;
      const bool val = (unsigned)c < (unsigned)NIN;
      float e = 0.f;
      if (val)
        e = g0 * Hs[c] + g1 * Hs[NIN + c] + g2 * Hs[2 * NIN + c] + g3 * Hs[3 * NIN + c];
      float v = e;
      #pragma unroll
      for (int off = 1; off < 64; off <<= 1) {
        float o = __shfl_up(v, off, 64);
        if (lane >= off) v += o;
      }
      const float m = carry[j] + v;
      if (val) {
        __bf16 b = (__bf16)m;
        tile[lane][dj] = *(const unsigned short*)&b;
      }
      carry[j] += __shfl(v, 63, 64);
    }
    __syncthreads();
    // store out: wave w handles rows w*16..w*16+15, 2 rows per wave-store
    #pragma unroll
    for (int rr = 0; rr < 16; rr += 2) {
      const int r = w * 16 + rr + (lane >> 5);
      const int cc = lane & 31;
      const int gcol = k0 + d0 + r + cc;   // == global c for tile[r][cc]
      if ((unsigned)gcol < (unsigned)NIN)
        Ms[(size_t)(k0 + r) * NIN + gcol] = tile[r][cc];
    }
    __syncthreads();
  }
}

// ============ GEMM: C[m][n] = sum_k A[m][k]*B[n][k] + bias[n] ============
// (byte-identical to round 3)
#define BK 32
#define KT (NIN / BK)        // 32
#define TILEBY 32768         // A 16K + B 16K per K-tile

__device__ __forceinline__ void gload16(const char* gsrc, char* lds) {
  __builtin_amdgcn_global_load_lds(
      (const __attribute__((address_space(1))) unsigned int*)gsrc,
      (__attribute__((address_space(3))) unsigned int*)lds, 16, 0, 0);
}

__global__ __launch_bounds__(512, 2) void gemm_kernel(
    const __bf16* __restrict__ A,   // [NTOK][NIN]
    const __bf16* __restrict__ B,   // [NOUT][NIN]
    const float* __restrict__ bias, // [NOUT]
    float* __restrict__ C) {        // [NTOK][NOUT]
  __shared__ __align__(16) char smem[4 * TILEBY];  // 128 KB

  const int tid = threadIdx.x;
  const int lane = tid & 63;
  const int lo = lane & 15;
  const int hi = lane >> 4;
  const int wid = tid >> 6;
  const int wr = wid >> 2;   // 0..1
  const int wc = wid & 3;    // 0..3

  // XCD-aware block swizzle (grid 256, 256%8==0)
  const int orig = blockIdx.x;
  const int wg = (orig & 7) * 32 + (orig >> 3);
  const int bx = wg & 15;
  const int by = wg >> 4;
  const int brow = by * 256;
  const int bcol = bx * 256;

  // staging: LDS dest linear; global src col = (P&63) ^ ((row>>1 &3)<<4)  [T2, rule 21]
  const char* Ab = (const char*)(A + (size_t)brow * NIN);
  const char* Bb = (const char*)(B + (size_t)bcol * NIN);
  size_t gofs[2];
  int lofs[2];
  #pragma unroll
  for (int l = 0; l < 2; ++l) {
    int P = (l * 512 + tid) * 16;          // 0..16K
    int row = P >> 6;
    int inner = (P & 63) ^ (((row >> 1) & 3) << 4);
    lofs[l] = P;
    gofs[l] = (size_t)row * (NIN * 2) + inner;
  }

  // fragment ds_read offsets (swizzled read side)
  const int kso = ((hi ^ ((lo >> 1) & 3)) << 4);
  const int abase = (wr * 128 + lo) * 64 + kso;            // + mi*1024
  const int bbase = 16384 + (wc * 64 + lo) * 64 + kso;     // + ni*1024

  f32x4 acc[8][4];
  #pragma unroll
  for (int i = 0; i < 8; ++i)
    #pragma unroll
    for (int j = 0; j < 4; ++j)
      acc[i][j] = (f32x4){0.f, 0.f, 0.f, 0.f};

  // ---- prologue: stage tiles 0 and 1 ----
  #pragma unroll
  for (int l = 0; l < 2; ++l) gload16(Ab + gofs[l], smem + lofs[l]);
  #pragma unroll
  for (int l = 0; l < 2; ++l) gload16(Bb + gofs[l], smem + 16384 + lofs[l]);
  #pragma unroll
  for (int l = 0; l < 2; ++l) gload16(Ab + 64 + gofs[l], smem + TILEBY + lofs[l]);
  #pragma unroll
  for (int l = 0; l < 2; ++l) gload16(Bb + 64 + gofs[l], smem + TILEBY + 16384 + lofs[l]);

  #pragma unroll 1
  for (int kt = 0; kt < KT; ++kt) {
    const char* buf = smem + (kt & 3) * TILEBY;
    char* sbuf = smem + ((kt + 2) & 3) * TILEBY;
    const int kg = (kt + 2) * 64;
    const bool dost = (kt + 2) < KT;

    asm volatile("s_waitcnt vmcnt(4)" ::: "memory");
    __builtin_amdgcn_s_barrier();

    // ---- phase A: stage A(kt+2); read A mi0-3 + all B; MFMA mi0-3 ----
    if (dost) {
      gload16(Ab + kg + gofs[0], sbuf + lofs[0]);
      gload16(Ab + kg + gofs[1], sbuf + lofs[1]);
    }
    bf16x8 af[4], bfr[4];
    #pragma unroll
    for (int mi = 0; mi < 4; ++mi)
      af[mi] = *(const bf16x8*)(buf + abase + mi * 1024);
    #pragma unroll
    for (int ni = 0; ni < 4; ++ni)
      bfr[ni] = *(const bf16x8*)(buf + bbase + ni * 1024);
    __builtin_amdgcn_s_setprio(1);
    #pragma unroll
    for (int mi = 0; mi < 4; ++mi)
      #pragma unroll
      for (int ni = 0; ni < 4; ++ni)
        acc[mi][ni] = __builtin_amdgcn_mfma_f32_16x16x32_bf16(af[mi], bfr[ni], acc[mi][ni], 0, 0, 0);
    __builtin_amdgcn_s_setprio(0);

    // ---- phase B: stage B(kt+2); read A mi4-7; MFMA mi4-7 ----
    if (dost) {
      gload16(Bb + kg + gofs[0], sbuf + 16384 + lofs[0]);
      gload16(Bb + kg + gofs[1], sbuf + 16384 + lofs[1]);
    }
    bf16x8 af2[4];
    #pragma unroll
    for (int mi = 0; mi < 4; ++mi)
      af2[mi] = *(const bf16x8*)(buf + abase + (mi + 4) * 1024);
    __builtin_amdgcn_s_setprio(1);
    #pragma unroll
    for (int mi = 0; mi < 4; ++mi)
      #pragma unroll
      for (int ni = 0; ni < 4; ++ni)
        acc[mi + 4][ni] = __builtin_amdgcn_mfma_f32_16x16x32_bf16(af2[mi], bfr[ni], acc[mi + 4][ni], 0, 0, 0);
    __builtin_amdgcn_s_setprio(0);
  }

  // ---- epilogue: D layout col=lane&15, row=(lane>>4)*4+reg ----
  #pragma unroll
  for (int ni = 0; ni < 4; ++ni) {
    const int col = bcol + wc * 64 + ni * 16 + lo;
    const float bv = bias[col];
    #pragma unroll
    for (int mi = 0; mi < 8; ++mi) {
      const int row0 = brow + wr * 128 + mi * 16 + hi * 4;
      float* Cp = C + (size_t)row0 * NOUT + col;
      Cp[0]                = acc[mi][ni][0] + bv;
      Cp[(size_t)NOUT]     = acc[mi][ni][1] + bv;
      Cp[2 * (size_t)NOUT] = acc[mi][ni][2] + bv;
      Cp[3 * (size_t)NOUT] = acc[mi][ni][3] + bv;
    }
  }
}

extern "C" void kernel_launch(void* const* d_in, const int* in_sizes, int n_in,
                              void* d_out, int out_size, void* d_ws, size_t ws_size,
                              hipStream_t stream) {
  const float* x = (const float*)d_in[0];
  const float* G = (const float*)d_in[1];
  const float* H = (const float*)d_in[2];
  const float* bias = (const float*)d_in[3];
  float* out = (float*)d_out;

  __bf16* xb = (__bf16*)d_ws;                                    // 8 MB
  __bf16* Mb = (__bf16*)((char*)d_ws + (size_t)NTOK * NIN * 2);  // 8 MB

  prep_kernel<<<256 + 2048, 256, 0, stream>>>(x, G, H, xb, Mb);
  gemm_kernel<<<256, 512, 0, stream>>>(xb, Mb, bias, out);
}